// Round 3
// baseline (284.003 us; speedup 1.0000x reference)
//
#include <hip/hip_runtime.h>
#include <math.h>
#include <limits.h>

#define M_ROWS 65536   // B*N = 64*1024
#define DD     256     // feature dim
#define KC     512     // codes
#define TILE_M 128     // rows per block
#define CHUNK  128     // codes per block (chunk)
#define NCH    (KC / CHUNK)   // 4 chunk-blocks per row-tile
#define KS     32      // k-slice staged in LDS

// numpy-style pairwise sum (8 accumulators, block 128) of squares of 128 floats.
__device__ __forceinline__ float pw128_sq(const float4* __restrict__ q) {
  float r[8];
  {
    float4 a = q[0], b = q[1];
    r[0] = __fmul_rn(a.x, a.x); r[1] = __fmul_rn(a.y, a.y);
    r[2] = __fmul_rn(a.z, a.z); r[3] = __fmul_rn(a.w, a.w);
    r[4] = __fmul_rn(b.x, b.x); r[5] = __fmul_rn(b.y, b.y);
    r[6] = __fmul_rn(b.z, b.z); r[7] = __fmul_rn(b.w, b.w);
  }
#pragma unroll
  for (int i = 2; i < 32; i += 2) {
    float4 a = q[i], b = q[i + 1];
    r[0] = __fadd_rn(r[0], __fmul_rn(a.x, a.x));
    r[1] = __fadd_rn(r[1], __fmul_rn(a.y, a.y));
    r[2] = __fadd_rn(r[2], __fmul_rn(a.z, a.z));
    r[3] = __fadd_rn(r[3], __fmul_rn(a.w, a.w));
    r[4] = __fadd_rn(r[4], __fmul_rn(b.x, b.x));
    r[5] = __fadd_rn(r[5], __fmul_rn(b.y, b.y));
    r[6] = __fadd_rn(r[6], __fmul_rn(b.z, b.z));
    r[7] = __fadd_rn(r[7], __fmul_rn(b.w, b.w));
  }
  return __fadd_rn(__fadd_rn(__fadd_rn(r[0], r[1]), __fadd_rn(r[2], r[3])),
                   __fadd_rn(__fadd_rn(r[4], r[5]), __fadd_rn(r[6], r[7])));
}

__global__ void sumsq_kernel(const float* __restrict__ x, float* __restrict__ s,
                             int nrows) {
  int r = blockIdx.x * blockDim.x + threadIdx.x;
  if (r >= nrows) return;
  const float4* q = (const float4*)(x + (size_t)r * DD);
  s[r] = __fadd_rn(pw128_sq(q), pw128_sq(q + 32));
}

// One block = one (row-tile, code-chunk) pair. Writes partial argmin to ws.
// LDS swizzle: float4-column q of row r stored at slot (q ^ ((r>>3)&7)).
__global__ __launch_bounds__(256) void vq_partial_kernel(
    const float* __restrict__ z, const float* __restrict__ cb,
    const float* __restrict__ s, const float* __restrict__ se,
    float* __restrict__ pd, int* __restrict__ pi) {
  __shared__ float4 zs4[TILE_M * 8];   // 16 KB (128 rows x 32 floats, swizzled)
  __shared__ float4 es4[CHUNK * 8];    // 16 KB (128 codes x 32 floats, swizzled)
  __shared__ float s_l[TILE_M];
  __shared__ float se_l[CHUNK];

  const int tid = threadIdx.x;
  const int tx = tid & 15, ty = tid >> 4;
  const int txs = tx & 7, tys = ty & 7;
  const int bid = blockIdx.x;
  const int mt = bid >> 2;             // row tile: adjacent blocks share it (L2)
  const int ch = bid & 3;              // code chunk
  const int r0 = mt * TILE_M;
  const int cbase = ch * CHUNK;

  if (tid < TILE_M) s_l[tid] = s[r0 + tid];
  if (tid < CHUNK) se_l[tid] = se[cbase + tid];
  // published by the first __syncthreads at the top of the ks loop

  float bestd[8];
  int   besti[8];
#pragma unroll
  for (int i = 0; i < 8; ++i) { bestd[i] = INFINITY; besti[i] = INT_MAX; }

  const float4* zg = (const float4*)z;
  const float4* cg = (const float4*)cb;

  float acc[8][8];
#pragma unroll
  for (int i = 0; i < 8; ++i)
#pragma unroll
    for (int j = 0; j < 8; ++j) acc[i][j] = 0.0f;

  for (int ks = 0; ks < DD / KS; ++ks) {    // 8 k-slices of 32
    __syncthreads();  // LDS reuse barrier (publishes prologue on iter 0)
    // stage z slice: 128 rows x 8 float4, swizzled
#pragma unroll
    for (int p = 0; p < 4; ++p) {
      int u = p * 256 + tid;
      int row = u >> 3, q = u & 7;
      zs4[(row << 3) | (q ^ ((row >> 3) & 7))] =
          zg[(size_t)(r0 + row) * 64 + ks * 8 + q];
    }
    // stage e slice: 128 codes x 8 float4, swizzled
#pragma unroll
    for (int p = 0; p < 4; ++p) {
      int u = p * 256 + tid;
      int crow = u >> 3, q = u & 7;
      es4[(crow << 3) | (q ^ ((crow >> 3) & 7))] =
          cg[(size_t)(cbase + crow) * 64 + ks * 8 + q];
    }
    __syncthreads();

#pragma unroll
    for (int k4 = 0; k4 < 8; ++k4) {
      const int kz = k4 ^ tys;
      const int ke = k4 ^ txs;
      float4 zf[8];
#pragma unroll
      for (int i = 0; i < 8; ++i) zf[i] = zs4[((ty * 8 + i) << 3) | kz];
#pragma unroll
      for (int j = 0; j < 8; ++j) {
        float4 ef = es4[((tx * 8 + j) << 3) | ke];
        // strict k-ascending FMA chain per (row, code) — bit-identical to ref
#pragma unroll
        for (int i = 0; i < 8; ++i) {
          acc[i][j] = __fmaf_rn(zf[i].x, ef.x, acc[i][j]);
          acc[i][j] = __fmaf_rn(zf[i].y, ef.y, acc[i][j]);
          acc[i][j] = __fmaf_rn(zf[i].z, ef.z, acc[i][j]);
          acc[i][j] = __fmaf_rn(zf[i].w, ef.w, acc[i][j]);
        }
      }
    }
  }

  // d = (s - 2*dot) + se, rounded exactly like the reference expression
#pragma unroll
  for (int i = 0; i < 8; ++i) {
    float s_r = s_l[ty * 8 + i];
#pragma unroll
    for (int j = 0; j < 8; ++j) {
      int code = cbase + tx * 8 + j;
      float d = __fadd_rn(__fsub_rn(s_r, __fmul_rn(2.0f, acc[i][j])),
                          se_l[code - cbase]);
      if (d < bestd[i] || (d == bestd[i] && code < besti[i])) {
        bestd[i] = d; besti[i] = code;
      }
    }
  }

  // argmin reduce across the 16 tx lanes (same wave), min-d then min-index
#pragma unroll
  for (int i = 0; i < 8; ++i) {
    float bd = bestd[i];
    int   bi = besti[i];
#pragma unroll
    for (int off = 1; off < 16; off <<= 1) {
      float od = __shfl_xor(bd, off, 64);
      int   oi = __shfl_xor(bi, off, 64);
      if (od < bd || (od == bd && oi < bi)) { bd = od; bi = oi; }
    }
    if (tx == 0) {
      int row = r0 + ty * 8 + i;
      pd[(size_t)ch * M_ROWS + row] = bd;
      pi[(size_t)ch * M_ROWS + row] = bi;
    }
  }
}

// Combine partial argmins (chunk-ascending => first-index tie-break preserved)
// + gather epilogue. One block = 128 rows.
__global__ __launch_bounds__(256) void combine_kernel(
    const float* __restrict__ z, const float* __restrict__ cb,
    const float* __restrict__ pd, const int* __restrict__ pi,
    float* __restrict__ out) {
  __shared__ int best_l[128];
  const int tid = threadIdx.x;
  const int r0 = blockIdx.x * 128;

  if (tid < 128) {
    int row = r0 + tid;
    float bd = INFINITY;
    int   bi = INT_MAX;
#pragma unroll
    for (int c = 0; c < NCH; ++c) {
      float d = pd[(size_t)c * M_ROWS + row];
      int   i2 = pi[(size_t)c * M_ROWS + row];
      if (d < bd || (d == bd && i2 < bi)) { bd = d; bi = i2; }
    }
    best_l[tid] = bi;
  }
  __syncthreads();

  const float4* zg = (const float4*)z;
  const float4* cg = (const float4*)cb;
  float4* out0 = (float4*)out;
  float4* out1 = (float4*)(out + (size_t)M_ROWS * DD);
#pragma unroll
  for (int it = 0; it < (128 * 64) / 256; ++it) {
    int u = it * 256 + tid;
    int row = u >> 6, c4 = u & 63;
    size_t gidx = (size_t)(r0 + row) * 64 + c4;
    float4 zv = zg[gidx];
    float4 cv = cg[(size_t)best_l[row] * 64 + c4];
    float4 o0;
    o0.x = __fadd_rn(zv.x, __fsub_rn(cv.x, zv.x));
    o0.y = __fadd_rn(zv.y, __fsub_rn(cv.y, zv.y));
    o0.z = __fadd_rn(zv.z, __fsub_rn(cv.z, zv.z));
    o0.w = __fadd_rn(zv.w, __fsub_rn(cv.w, zv.w));
    out0[gidx] = o0;
    out1[gidx] = cv;
  }
}

extern "C" void kernel_launch(void* const* d_in, const int* in_sizes, int n_in,
                              void* d_out, int out_size, void* d_ws, size_t ws_size,
                              hipStream_t stream) {
  const float* z  = (const float*)d_in[0];   // [65536, 256]
  const float* cb = (const float*)d_in[1];   // [512, 256]
  float* out = (float*)d_out;                // 2 x [65536, 256] concat
  float* s  = (float*)d_ws;                  // ||z||^2 per row      (64K f)
  float* se = s + M_ROWS;                    // ||e||^2 per code     (512 f)
  float* pd = se + KC;                       // partial best-d  [NCH][M_ROWS]
  int*   pi = (int*)(pd + (size_t)NCH * M_ROWS);  // partial best-i

  sumsq_kernel<<<M_ROWS / 256, 256, 0, stream>>>(z, s, M_ROWS);
  sumsq_kernel<<<KC / 256, 256, 0, stream>>>(cb, se, KC);
  vq_partial_kernel<<<(M_ROWS / TILE_M) * NCH, 256, 0, stream>>>(z, cb, s, se, pd, pi);
  combine_kernel<<<M_ROWS / 128, 256, 0, stream>>>(z, cb, pd, pi, out);
}